// Round 2
// baseline (208.456 us; speedup 1.0000x reference)
//
#include <hip/hip_runtime.h>

// NormalComponentReconstructionLoss: mean_n || r - H (H^T r) ||^2
//   r = rec - pts  (per-point, D=3),  H = frame[n] in R^{3x2}
// Memory-bound streaming reduction: 48 B/point read, 1 scalar out.
// Roofline: 192 MB / 6.3 TB/s ~= 31 us.

#define THREADS 256
#define BLOCKS  2048
#define NWAVES  (THREADS / 64)

__global__ __launch_bounds__(THREADS) void ncrl_partial(
    const float* __restrict__ pts,
    const float* __restrict__ rec,
    const float* __restrict__ frame,
    float* __restrict__ partial,
    int nGroups)            // groups of 4 points
{
    const float4* __restrict__ P4 = reinterpret_cast<const float4*>(pts);
    const float4* __restrict__ R4 = reinterpret_cast<const float4*>(rec);
    const float4* __restrict__ F4 = reinterpret_cast<const float4*>(frame);

    float acc = 0.0f;
    const int stride = gridDim.x * blockDim.x;
    for (int g = blockIdx.x * blockDim.x + threadIdx.x; g < nGroups; g += stride) {
        // 4 points = 12 floats of pts/rec, 24 floats of frame — all float4, coalesced
        float4 a0 = P4[3 * g + 0], a1 = P4[3 * g + 1], a2 = P4[3 * g + 2];
        float4 b0 = R4[3 * g + 0], b1 = R4[3 * g + 1], b2 = R4[3 * g + 2];
        float4 h0 = F4[6 * g + 0], h1 = F4[6 * g + 1], h2 = F4[6 * g + 2];
        float4 h3 = F4[6 * g + 3], h4 = F4[6 * g + 4], h5 = F4[6 * g + 5];

        const float pa[12] = {a0.x, a0.y, a0.z, a0.w, a1.x, a1.y,
                              a1.z, a1.w, a2.x, a2.y, a2.z, a2.w};
        const float pb[12] = {b0.x, b0.y, b0.z, b0.w, b1.x, b1.y,
                              b1.z, b1.w, b2.x, b2.y, b2.z, b2.w};
        const float ph[24] = {h0.x, h0.y, h0.z, h0.w, h1.x, h1.y, h1.z, h1.w,
                              h2.x, h2.y, h2.z, h2.w, h3.x, h3.y, h3.z, h3.w,
                              h4.x, h4.y, h4.z, h4.w, h5.x, h5.y, h5.z, h5.w};

#pragma unroll
        for (int k = 0; k < 4; ++k) {   // static indices after full unroll (rule #20)
            const float r0 = pb[3 * k + 0] - pa[3 * k + 0];
            const float r1 = pb[3 * k + 1] - pa[3 * k + 1];
            const float r2 = pb[3 * k + 2] - pa[3 * k + 2];
            const float H00 = ph[6 * k + 0], H01 = ph[6 * k + 1];
            const float H10 = ph[6 * k + 2], H11 = ph[6 * k + 3];
            const float H20 = ph[6 * k + 4], H21 = ph[6 * k + 5];
            const float c0 = H00 * r0 + H10 * r1 + H20 * r2;
            const float c1 = H01 * r0 + H11 * r1 + H21 * r2;
            const float d0 = r0 - (H00 * c0 + H01 * c1);
            const float d1 = r1 - (H10 * c0 + H11 * c1);
            const float d2 = r2 - (H20 * c0 + H21 * c1);
            acc += d0 * d0 + d1 * d1 + d2 * d2;
        }
    }

    // wave-64 butterfly reduce
#pragma unroll
    for (int off = 32; off > 0; off >>= 1)
        acc += __shfl_down(acc, off, 64);

    __shared__ float wsum[NWAVES];
    const int lane = threadIdx.x & 63;
    const int wv   = threadIdx.x >> 6;
    if (lane == 0) wsum[wv] = acc;
    __syncthreads();
    if (threadIdx.x == 0) {
        float s = 0.0f;
#pragma unroll
        for (int w = 0; w < NWAVES; ++w) s += wsum[w];
        partial[blockIdx.x] = s;
    }
}

__global__ __launch_bounds__(THREADS) void ncrl_finalize(
    const float* __restrict__ partial,
    const float* __restrict__ pts,
    const float* __restrict__ rec,
    const float* __restrict__ frame,
    float* __restrict__ out,
    int nPartial, int nTailStart, int nPoints)
{
    double acc = 0.0;
    for (int i = threadIdx.x; i < nPartial; i += THREADS)
        acc += (double)partial[i];

    // scalar tail points (N % 4), thread 0 only — empty for N=4M
    if (threadIdx.x == 0) {
        for (int n = nTailStart; n < nPoints; ++n) {
            const float r0 = rec[3 * n + 0] - pts[3 * n + 0];
            const float r1 = rec[3 * n + 1] - pts[3 * n + 1];
            const float r2 = rec[3 * n + 2] - pts[3 * n + 2];
            const float H00 = frame[6 * n + 0], H01 = frame[6 * n + 1];
            const float H10 = frame[6 * n + 2], H11 = frame[6 * n + 3];
            const float H20 = frame[6 * n + 4], H21 = frame[6 * n + 5];
            const float c0 = H00 * r0 + H10 * r1 + H20 * r2;
            const float c1 = H01 * r0 + H11 * r1 + H21 * r2;
            const float d0 = r0 - (H00 * c0 + H01 * c1);
            const float d1 = r1 - (H10 * c0 + H11 * c1);
            const float d2 = r2 - (H20 * c0 + H21 * c1);
            acc += (double)(d0 * d0 + d1 * d1 + d2 * d2);
        }
    }

#pragma unroll
    for (int off = 32; off > 0; off >>= 1)
        acc += __shfl_down(acc, off, 64);

    __shared__ double wsum[NWAVES];
    const int lane = threadIdx.x & 63;
    const int wv   = threadIdx.x >> 6;
    if (lane == 0) wsum[wv] = acc;
    __syncthreads();
    if (threadIdx.x == 0) {
        double total = 0.0;
#pragma unroll
        for (int w = 0; w < NWAVES; ++w) total += wsum[w];
        out[0] = (float)(total / (double)nPoints);
    }
}

extern "C" void kernel_launch(void* const* d_in, const int* in_sizes, int n_in,
                              void* d_out, int out_size, void* d_ws, size_t ws_size,
                              hipStream_t stream) {
    const float* pts   = (const float*)d_in[0];   // [N,3]
    const float* rec   = (const float*)d_in[1];   // [N,3]
    const float* frame = (const float*)d_in[2];   // [N,3,2]
    float* out = (float*)d_out;

    const int N       = in_sizes[0] / 3;
    const int nGroups = N / 4;          // 4-point groups, exact for N=4M
    const int tail    = nGroups * 4;    // first tail point index

    float* partial = (float*)d_ws;      // BLOCKS floats, all written every launch

    ncrl_partial<<<BLOCKS, THREADS, 0, stream>>>(pts, rec, frame, partial, nGroups);
    ncrl_finalize<<<1, THREADS, 0, stream>>>(partial, pts, rec, frame, out,
                                             BLOCKS, tail, N);
}

// Round 3
// 207.612 us; speedup vs baseline: 1.0041x; 1.0041x over previous
//
#include <hip/hip_runtime.h>
#include <stdint.h>

// NormalComponentReconstructionLoss: mean_n || r - H (H^T r) ||^2
//   r = rec - pts  (D=3),  H = frame[n] in R^{3x2}
// Memory-bound streaming reduction: 48 B/point read, 192 MB total.
// R2 diagnosis: AoS float4 loads had 48/96 B per-lane stride -> ~3x memory
// request inflation -> 2.6 TB/s effective. Fix: lane-contiguous
// global_load_lds staging (12 x 1KiB coalesced loads per 256-pt wave slice),
// compute from LDS with bank-aware read widths.

#define THREADS 256
#define NWAVES  (THREADS / 64)
#define BLOCKS  768                 // 3 blocks/CU at 48KB LDS each
#define WAVE_LDS 12288              // 256 points * 48 B

__device__ __forceinline__ void gload_lds16(const void* g, void* l) {
    __builtin_amdgcn_global_load_lds(
        (const __attribute__((address_space(1))) unsigned int*)g,
        (__attribute__((address_space(3))) unsigned int*)l, 16, 0, 0);
}

__global__ __launch_bounds__(THREADS) void ncrl_partial(
    const float* __restrict__ pts,
    const float* __restrict__ rec,
    const float* __restrict__ frame,
    float* __restrict__ partial,
    int nSlices)                    // 256-point slices
{
    __shared__ char stage[WAVE_LDS * NWAVES];   // 48 KB, disjoint per wave
    __shared__ float wsum[NWAVES];

    const int lane = threadIdx.x & 63;
    const int wv   = threadIdx.x >> 6;
    char* wbase = stage + wv * WAVE_LDS;
    const float* Lp = (const float*)(wbase);            // 768 floats pts
    const float* Lr = (const float*)(wbase + 3072);     // 768 floats rec
    const float* Lf = (const float*)(wbase + 6144);     // 1536 floats frame

    const float4* P4 = (const float4*)pts;
    const float4* R4 = (const float4*)rec;
    const float4* F4 = (const float4*)frame;

    const int gw0      = blockIdx.x * NWAVES + wv;
    const int gwStride = gridDim.x * NWAVES;

    float acc = 0.0f;
    for (int s = gw0; s < nSlices; s += gwStride) {
        // previous iter's LDS reads must finish before staging overwrites
        asm volatile("s_waitcnt lgkmcnt(0)" ::: "memory");

        // 12 lane-contiguous 1 KiB global->LDS loads (wave-uniform LDS base)
        const float4* Pg = P4 + (size_t)s * 192 + lane;   // 256*3/4 f4 per slice
        const float4* Rg = R4 + (size_t)s * 192 + lane;
        const float4* Fg = F4 + (size_t)s * 384 + lane;   // 256*6/4 f4 per slice
#pragma unroll
        for (int i = 0; i < 3; ++i) gload_lds16(Pg + i * 64, wbase + i * 1024);
#pragma unroll
        for (int i = 0; i < 3; ++i) gload_lds16(Rg + i * 64, wbase + 3072 + i * 1024);
#pragma unroll
        for (int i = 0; i < 6; ++i) gload_lds16(Fg + i * 64, wbase + 6144 + i * 1024);

        asm volatile("s_waitcnt vmcnt(0)" ::: "memory");  // wave-local: own slice only

#pragma unroll
        for (int k = 0; k < 4; ++k) {
            const int p = k * 64 + lane;    // consecutive lanes -> consecutive points
            // pts/rec: 3x b32 (stride 3 dwords -> 2-way bank alias, free)
            const float a0 = Lp[3 * p], a1 = Lp[3 * p + 1], a2 = Lp[3 * p + 2];
            const float b0 = Lr[3 * p], b1 = Lr[3 * p + 1], b2 = Lr[3 * p + 2];
            // frame: 3x b64, 8B-aligned (24p bytes), 4-way alias (1.58x, fine)
            const float2 h0 = *(const float2*)(Lf + 6 * p);      // H00 H01
            const float2 h1 = *(const float2*)(Lf + 6 * p + 2);  // H10 H11
            const float2 h2 = *(const float2*)(Lf + 6 * p + 4);  // H20 H21

            const float r0 = b0 - a0, r1 = b1 - a1, r2 = b2 - a2;
            const float c0 = h0.x * r0 + h1.x * r1 + h2.x * r2;
            const float c1 = h0.y * r0 + h1.y * r1 + h2.y * r2;
            const float d0 = r0 - (h0.x * c0 + h0.y * c1);
            const float d1 = r1 - (h1.x * c0 + h1.y * c1);
            const float d2 = r2 - (h2.x * c0 + h2.y * c1);
            acc += d0 * d0 + d1 * d1 + d2 * d2;
        }
    }

    // wave-64 butterfly reduce
#pragma unroll
    for (int off = 32; off > 0; off >>= 1)
        acc += __shfl_down(acc, off, 64);

    if (lane == 0) wsum[wv] = acc;
    __syncthreads();
    if (threadIdx.x == 0) {
        float ssum = 0.0f;
#pragma unroll
        for (int w = 0; w < NWAVES; ++w) ssum += wsum[w];
        partial[blockIdx.x] = ssum;
    }
}

__global__ __launch_bounds__(THREADS) void ncrl_finalize(
    const float* __restrict__ partial,
    const float* __restrict__ pts,
    const float* __restrict__ rec,
    const float* __restrict__ frame,
    float* __restrict__ out,
    int nPartial, int nTailStart, int nPoints)
{
    double acc = 0.0;
    for (int i = threadIdx.x; i < nPartial; i += THREADS)
        acc += (double)partial[i];

    // scalar tail (N % 256), empty for N=4M
    if (threadIdx.x == 0) {
        for (int n = nTailStart; n < nPoints; ++n) {
            const float r0 = rec[3 * n + 0] - pts[3 * n + 0];
            const float r1 = rec[3 * n + 1] - pts[3 * n + 1];
            const float r2 = rec[3 * n + 2] - pts[3 * n + 2];
            const float H00 = frame[6 * n + 0], H01 = frame[6 * n + 1];
            const float H10 = frame[6 * n + 2], H11 = frame[6 * n + 3];
            const float H20 = frame[6 * n + 4], H21 = frame[6 * n + 5];
            const float c0 = H00 * r0 + H10 * r1 + H20 * r2;
            const float c1 = H01 * r0 + H11 * r1 + H21 * r2;
            const float d0 = r0 - (H00 * c0 + H01 * c1);
            const float d1 = r1 - (H10 * c0 + H11 * c1);
            const float d2 = r2 - (H20 * c0 + H21 * c1);
            acc += (double)(d0 * d0 + d1 * d1 + d2 * d2);
        }
    }

#pragma unroll
    for (int off = 32; off > 0; off >>= 1)
        acc += __shfl_down(acc, off, 64);

    __shared__ double dsum[NWAVES];
    const int lane = threadIdx.x & 63;
    const int wv   = threadIdx.x >> 6;
    if (lane == 0) dsum[wv] = acc;
    __syncthreads();
    if (threadIdx.x == 0) {
        double total = 0.0;
#pragma unroll
        for (int w = 0; w < NWAVES; ++w) total += dsum[w];
        out[0] = (float)(total / (double)nPoints);
    }
}

extern "C" void kernel_launch(void* const* d_in, const int* in_sizes, int n_in,
                              void* d_out, int out_size, void* d_ws, size_t ws_size,
                              hipStream_t stream) {
    const float* pts   = (const float*)d_in[0];   // [N,3]
    const float* rec   = (const float*)d_in[1];   // [N,3]
    const float* frame = (const float*)d_in[2];   // [N,3,2]
    float* out = (float*)d_out;

    const int N       = in_sizes[0] / 3;
    const int nSlices = N / 256;          // exact for N=4M (15625 slices)
    const int tail    = nSlices * 256;

    float* partial = (float*)d_ws;        // BLOCKS floats, all written every launch

    ncrl_partial<<<BLOCKS, THREADS, 0, stream>>>(pts, rec, frame, partial, nSlices);
    ncrl_finalize<<<1, THREADS, 0, stream>>>(partial, pts, rec, frame, out,
                                             BLOCKS, tail, N);
}